// Round 5
// baseline (896.271 us; speedup 1.0000x reference)
//
#include <hip/hip_runtime.h>
#include <hip/hip_bf16.h>

#define NN 100000
#define NE 1600000
#define D 64
#define C 16
#define NEG_SLOPE 0.01f

#define NBINS 512      // receiver bins
#define BINW 196       // nodes per bin (ceil 100000/512); fits 8-bit r_local
#define DEPTH 16       // LDS records per bin == flush unit (64B)
#define CAP 3584       // per-bin record capacity (mean 3125, +8 sigma)
#define B_BIN 128      // binning blocks
#define EPB 12500      // edges per binning block
#define NROUND 49      // ceil(EPB/256)
#define B_HIST 50      // cnt_s histogram blocks
#define EPH 32000      // edges per hist block
#define GB0 (B_BIN + B_HIST)
#define B_GEMM 6250    // 4 waves/block, 4 nodes/wave -> 100000 nodes

typedef unsigned int u32;
typedef unsigned short u16;

__device__ __forceinline__ float bf2f(u32 u) { return __uint_as_float(u << 16); }
__device__ __forceinline__ u16 f2bf(float f) {
    __hip_bfloat16 b = __float2bfloat16(f);   // RNE
    return *reinterpret_cast<u16*>(&b);
}

// ==== K1: [bin-blocks: receiver-binned record build] | [hist-blocks: cnt_s] | [gemm-blocks: h] ====
__global__ __launch_bounds__(256) void k1(
        const int* __restrict__ senders, const int* __restrict__ receivers,
        const float* __restrict__ nodes, const float* __restrict__ W0,
        const float* __restrict__ b0,
        int* __restrict__ cnt_s, int* __restrict__ gcur, u32* __restrict__ grec,
        u16* __restrict__ h) {
    __shared__ u32 lbuf[NBINS][DEPTH];   // 32 KB
    __shared__ int lcnt[NBINS];          // 2 KB
    int bid = blockIdx.x, t = threadIdx.x;

    if (bid < B_BIN) {
        // ---- receiver binning with LDS-staged 64B flushes ----
        for (int i = t; i < NBINS; i += 256) lcnt[i] = 0;
        __syncthreads();
        int e0 = bid * EPB;
        int sN = senders[e0 + t], rN = receivers[e0 + t];   // round-0 prefetch (always valid)
        for (int rnd = 0; rnd < NROUND; ++rnd) {
            int sC = sN, rC = rN;
            bool vC = (rnd * 256 + t) < EPB;
            int nxt = (rnd + 1) * 256 + t;
            if (nxt < EPB) { sN = senders[e0 + nxt]; rN = receivers[e0 + nxt]; }
            if (vC) {
                u32 ur = (u32)rC;
                int bin = (int)(ur / BINW);
                u32 rec = ((ur - (u32)bin * BINW) << 24) | (u32)sC;  // r_local<=195, s<2^17
                int p = atomicAdd(&lcnt[bin], 1);
                if (p < DEPTH) lbuf[bin][p] = rec;
                else {  // rare overflow: correct direct path
                    int gp = atomicAdd(&gcur[bin], 1);
                    if (gp < CAP) grec[(size_t)bin * CAP + gp] = rec;
                }
            }
            __syncthreads();
            for (int bin = t; bin < NBINS; bin += 256) {
                if (lcnt[bin] >= DEPTH) {
                    int pos = atomicAdd(&gcur[bin], DEPTH);
                    if (pos + DEPTH <= CAP) {   // steady state: pos%16==0 -> 64B-aligned full line
                        uint4* dst = (uint4*)(grec + (size_t)bin * CAP + pos);
                        const uint4* src = (const uint4*)(&lbuf[bin][0]);
                        dst[0] = src[0]; dst[1] = src[1]; dst[2] = src[2]; dst[3] = src[3];
                    } else {
                        for (int k = 0; k < DEPTH; ++k) {
                            int gp = pos + k;
                            if (gp < CAP) grec[(size_t)bin * CAP + gp] = lbuf[bin][k];
                        }
                    }
                    lcnt[bin] = 0;
                }
            }
            __syncthreads();
        }
        // drain remainders (<16 per bin)
        for (int bin = t; bin < NBINS; bin += 256) {
            int n = lcnt[bin]; if (n > DEPTH) n = DEPTH;
            if (n > 0) {
                int pos = atomicAdd(&gcur[bin], n);
                for (int k = 0; k < n; ++k) {
                    int gp = pos + k;
                    if (gp < CAP) grec[(size_t)bin * CAP + gp] = lbuf[bin][k];
                }
            }
        }
    } else if (bid < GB0) {
        // ---- sender out-degree histogram (fire-and-forget atomics) ----
        int e0 = (bid - B_BIN) * EPH, e1 = e0 + EPH;
        for (int e = e0 + t; e < e1; e += 256)
            atomicAdd(&cnt_s[senders[e]], 1);
    } else {
        // ---- layer-1 dense, unnormalized, bf16 out; 4 nodes per wave ----
        int wv = (bid - GB0) * 4 + (t >> 6);
        int lane = t & 63;
        int nsub = lane >> 4, q = lane & 15;       // lane -> (node_sub, feat-quad)
        int node = wv * 4 + nsub;
        const float* __restrict__ row = nodes + (size_t)node * D;
        float4 acc = ((const float4*)b0)[q];
#pragma unroll 16
        for (int k = 0; k < D; ++k) {
            float rk = row[k];
            float4 w4 = ((const float4*)(W0 + k * D))[q];
            acc.x = fmaf(rk, w4.x, acc.x);
            acc.y = fmaf(rk, w4.y, acc.y);
            acc.z = fmaf(rk, w4.z, acc.z);
            acc.w = fmaf(rk, w4.w, acc.w);
        }
        uint2 pk;
        pk.x = (u32)f2bf(acc.x) | ((u32)f2bf(acc.y) << 16);
        pk.y = (u32)f2bf(acc.z) | ((u32)f2bf(acc.w) << 16);
        *(uint2*)(h + (size_t)node * D + q * 4) = pk;
    }
}

// ==== K2: per-bin LDS f32 aggregation + sender/recv norm + leaky + layer2 + sigmoid -> z ====
__global__ __launch_bounds__(512) void k2(
        const int* __restrict__ cnt_s, const int* __restrict__ gcur,
        const u32* __restrict__ grec, const u16* __restrict__ h,
        const float* __restrict__ W1, const float* __restrict__ b1,
        u16* __restrict__ z) {
    __shared__ float acc[BINW][D];   // 50.2 KB
    __shared__ int ldeg[BINW];
    __shared__ float sW1[D * C];     // 4 KB
    int bin = blockIdx.x, t = threadIdx.x;
    for (int i = t; i < BINW * D; i += 512) ((float*)acc)[i] = 0.f;
    for (int i = t; i < BINW; i += 512) ldeg[i] = 0;
    for (int i = t; i < D * C; i += 512) sW1[i] = W1[i];
    __syncthreads();

    int cnt = gcur[bin]; if (cnt > CAP) cnt = CAP;
    int lane = t & 63, w = t >> 6;            // 8 waves
    int half = lane >> 5, hl = lane & 31;     // 2 edges per wave-step
    for (int base = w * 64; base < cnt; base += 512) {
        int lim = cnt - base; if (lim > 64) lim = 64;
        u32 my = (lane < lim) ? grec[(size_t)bin * CAP + base + lane] : 0u;
        for (int j = 0; j < lim; j += 2) {
            int ei = j + half;
            u32 rec = __shfl(my, ei, 64);
            if (ei < lim) {
                int s = (int)(rec & 0x1FFFFu);
                int rl = (int)(rec >> 24);
                int ds = cnt_s[s];
                float rs = rsqrtf((float)(ds > 1 ? ds : 1));   // sender norm
                u32 w2 = *(const u32*)(h + (size_t)s * D + hl * 2);
                atomicAdd(&acc[rl][2 * hl],     rs * bf2f(w2 & 0xffffu));
                atomicAdd(&acc[rl][2 * hl + 1], rs * bf2f(w2 >> 16));
                if (hl == 0) atomicAdd(&ldeg[rl], 1);
            }
        }
    }
    __syncthreads();

    int nbase = bin * BINW;
    int nodes_in = NN - nbase;
    if (nodes_in > BINW) nodes_in = BINW;
    if (nodes_in < 0) nodes_in = 0;
    // recv norm + leaky, in place
    for (int i = t; i < nodes_in * D; i += 512) {
        int n = i >> 6, f = i & 63;
        int dg = ldeg[n];
        float rr = rsqrtf((float)(dg > 1 ? dg : 1));
        float v = acc[n][f] * rr;
        acc[n][f] = (v >= 0.f) ? v : NEG_SLOPE * v;
    }
    __syncthreads();
    // layer 2 + sigmoid
    for (int i = t; i < nodes_in * C; i += 512) {
        int n = i >> 4, c = i & 15;
        float p = b1[c];
#pragma unroll
        for (int f = 0; f < D; ++f)
            p = fmaf(acc[n][f], sW1[f * C + c], p);
        float zc = 1.f / (1.f + expf(-p));
        z[(size_t)(nbase + n) * C + c] = f2bf(zc);
    }
}

// ==== K3: per-bin LDS aggregation of z -> out (written exactly once) ====
__global__ __launch_bounds__(256) void k3(
        const int* __restrict__ gcur, const u32* __restrict__ grec,
        const u16* __restrict__ z, float* __restrict__ out) {
    __shared__ float acc2[BINW][C];  // 12.5 KB
    int bin = blockIdx.x, t = threadIdx.x;
    for (int i = t; i < BINW * C; i += 256) ((float*)acc2)[i] = 0.f;
    __syncthreads();

    int cnt = gcur[bin]; if (cnt > CAP) cnt = CAP;
    int lane = t & 63, w = t >> 6;          // 4 waves
    int g = lane >> 3, p = lane & 7;        // 8 edges per wave-step
    for (int base = w * 64; base < cnt; base += 256) {
        int lim = cnt - base; if (lim > 64) lim = 64;
        u32 my = (lane < lim) ? grec[(size_t)bin * CAP + base + lane] : 0u;
        for (int j = 0; j < lim; j += 8) {
            int ei = j + g;
            u32 rec = __shfl(my, ei, 64);
            if (ei < lim) {
                int s = (int)(rec & 0x1FFFFu);
                int rl = (int)(rec >> 24);
                u32 w2 = *(const u32*)(z + (size_t)s * C + p * 2);
                atomicAdd(&acc2[rl][2 * p],     bf2f(w2 & 0xffffu));
                atomicAdd(&acc2[rl][2 * p + 1], bf2f(w2 >> 16));
            }
        }
    }
    __syncthreads();

    int nbase = bin * BINW;
    int nodes_in = NN - nbase;
    if (nodes_in > BINW) nodes_in = BINW;
    if (nodes_in < 0) nodes_in = 0;
    for (int i = t; i < nodes_in * C; i += 256)
        out[(size_t)nbase * C + i] = ((float*)acc2)[i];
}

extern "C" void kernel_launch(void* const* d_in, const int* in_sizes, int n_in,
                              void* d_out, int out_size, void* d_ws, size_t ws_size,
                              hipStream_t stream) {
    const float* nodes     = (const float*)d_in[0];
    const int*   senders   = (const int*)d_in[1];
    const int*   receivers = (const int*)d_in[2];
    const float* W0        = (const float*)d_in[3];
    const float* b0        = (const float*)d_in[4];
    const float* W1        = (const float*)d_in[5];
    const float* b1        = (const float*)d_in[6];
    float* out = (float*)d_out;

    // workspace layout (~23.7 MB)
    char* wsb = (char*)d_ws;
    int*  cnt_s = (int*)wsb;                       // 400000 B
    int*  gcur  = (int*)(wsb + 400000);            // 2048 B
    u32*  grec  = (u32*)(wsb + 402048);            // 512*3584*4 = 7340032 B
    u16*  h     = (u16*)(wsb + 7742080);           // 100000*64*2 = 12800000 B
    u16*  z     = (u16*)(wsb + 20542080);          // 100000*16*2 = 3200000 B

    hipMemsetAsync(wsb, 0, 402048, stream);        // cnt_s + gcur

    k1<<<GB0 + B_GEMM, 256, 0, stream>>>(senders, receivers, nodes, W0, b0,
                                         cnt_s, gcur, grec, h);
    k2<<<NBINS, 512, 0, stream>>>(cnt_s, gcur, grec, h, W1, b1, z);
    k3<<<NBINS, 256, 0, stream>>>(gcur, grec, z, out);
}

// Round 6
// 319.423 us; speedup vs baseline: 2.8059x; 2.8059x over previous
//
#include <hip/hip_runtime.h>
#include <hip/hip_bf16.h>

#define NN 100000
#define NE 1600000
#define D 64
#define C 16
#define NEG_SLOPE 0.01f
#define MCAP 64        // bucket capacity per node; in-degree ~ Poisson(16), P(>64) ~ 0

// sender-degree histogram partitioning
#define NRANGE 8       // node ranges
#define RW 12544       // range width (8*12544 = 100352 >= NN)
#define WPR 3136       // u32 words per range (RW/4)
#define NSLICE 64      // edge slices
#define EPS 25000      // edges per slice (64*25000 = NE)
#define B_HIST (NRANGE * NSLICE)   // 512 hist blocks

#define B_BUILD 6250   // 256 edges/block = NE
#define B_GEMM 6250    // 4 waves x 4 nodes = 16 nodes/block

typedef unsigned int u32;
typedef unsigned short u16;

__device__ __forceinline__ float bf2f(u32 u) { return __uint_as_float(u << 16); }
__device__ __forceinline__ u16 f2bf(float f) {
    __hip_bfloat16 b = __float2bfloat16(f);   // RNE
    return *reinterpret_cast<u16*>(&b);
}

// ==== kA: [build: bucket scatter + cursor] | [gemm: layer-1 dense] | [hist: sender-degree partials] ====
__global__ __launch_bounds__(256) void kA(
        const int* __restrict__ senders, const int* __restrict__ receivers,
        const float* __restrict__ nodes, const float* __restrict__ W0,
        const float* __restrict__ b0,
        int* __restrict__ cnt_r, int* __restrict__ bucket,
        u16* __restrict__ h, u32* __restrict__ part) {
    __shared__ u32 smh[WPR];   // 12.5 KB (hist role only; occupancy unaffected)
    int bid = blockIdx.x, t = threadIdx.x;

    if (bid < 2 * B_BUILD) {
        if ((bid & 1) == 0) {
            // ---- bucket build: cursor atomic + scattered store ----
            int e = (bid >> 1) * 256 + t;            // exactly NE threads
            int s = senders[e];
            int r = receivers[e];
            int slot = atomicAdd(&cnt_r[r], 1);
            if (slot < MCAP) bucket[r * MCAP + slot] = s;   // guard: memory safety
        } else {
            // ---- layer-1 dense, unnormalized, bf16 out; 4 nodes per wave ----
            int wv = (bid >> 1) * 4 + (t >> 6);
            int lane = t & 63;
            int nsub = lane >> 4, q = lane & 15;     // (node_sub, feat-quad)
            int node = wv * 4 + nsub;
            const float* __restrict__ row = nodes + (size_t)node * D;
            float4 acc = ((const float4*)b0)[q];
#pragma unroll 16
            for (int k = 0; k < D; ++k) {
                float rk = row[k];
                float4 w4 = ((const float4*)(W0 + k * D))[q];
                acc.x = fmaf(rk, w4.x, acc.x);
                acc.y = fmaf(rk, w4.y, acc.y);
                acc.z = fmaf(rk, w4.z, acc.z);
                acc.w = fmaf(rk, w4.w, acc.w);
            }
            uint2 pk;
            pk.x = (u32)f2bf(acc.x) | ((u32)f2bf(acc.y) << 16);
            pk.y = (u32)f2bf(acc.z) | ((u32)f2bf(acc.w) << 16);
            *(uint2*)(h + (size_t)node * D + q * 4) = pk;
        }
    } else {
        // ---- sender-degree LDS u8 histogram over one (range, slice) ----
        int hb = bid - 2 * B_BUILD;                  // [0, 512)
        int rr = hb & 7, sl = hb >> 3;
        int lo = rr * RW;
        for (int i = t; i < WPR; i += 256) smh[i] = 0u;
        __syncthreads();
        const int* __restrict__ sp = senders + sl * EPS;
        for (int i = t; i < EPS; i += 256) {
            int local = sp[i] - lo;
            if ((u32)local < (u32)RW)
                atomicAdd(&smh[local >> 2], 1u << ((local & 3) * 8));
        }
        __syncthreads();
        u32* __restrict__ dst = part + (size_t)hb * WPR;
        for (int i = t; i < WPR; i += 256) dst[i] = smh[i];
    }
}

// ==== k0b: merge 64 u8 partials per range -> rnorm_s = rsqrt(max(deg_s,1)) ====
__global__ __launch_bounds__(256) void k0b(const u32* __restrict__ part,
                                           float* __restrict__ rnorm_s) {
    int tid = blockIdx.x * 256 + threadIdx.x;        // 98*256 = 25088 = NRANGE*WPR
    int rr = tid / WPR;
    int w = tid - rr * WPR;
    const u32* __restrict__ p = part + (size_t)rr * WPR + w;
    u32 acc0 = 0, acc1 = 0;                          // 16-bit lanes, max 64*255 < 65536
#pragma unroll 8
    for (int sl = 0; sl < NSLICE; ++sl) {
        u32 v = p[(size_t)(sl * 8) * WPR];
        acc0 += v & 0x00FF00FFu;
        acc1 += (v >> 8) & 0x00FF00FFu;
    }
    int node = rr * RW + w * 4;
    u32 c0 = acc0 & 0xFFFFu, c1 = acc1 & 0xFFFFu, c2 = acc0 >> 16, c3 = acc1 >> 16;
    if (node + 3 < NN) {
        float4 o;
        o.x = rsqrtf((float)(c0 > 1u ? c0 : 1u));
        o.y = rsqrtf((float)(c1 > 1u ? c1 : 1u));
        o.z = rsqrtf((float)(c2 > 1u ? c2 : 1u));
        o.w = rsqrtf((float)(c3 > 1u ? c3 : 1u));
        *(float4*)(rnorm_s + node) = o;
    } else {
        u32 cc[4] = {c0, c1, c2, c3};
        for (int k = 0; k < 4; ++k)
            if (node + k < NN)
                rnorm_s[node + k] = rsqrtf((float)(cc[k] > 1u ? cc[k] : 1u));
    }
}

// ==== kB: agg1 (sender norm) + recv norm + leaky + layer2 + sigmoid -> z ====
// one wave per node; 4 edges per wave-step (quarter-wave gathers 64 bf16 feats via uint2)
__global__ __launch_bounds__(256) void kB(
        const int* __restrict__ cnt_r, const int* __restrict__ bucket,
        const float* __restrict__ rnorm_s, const u16* __restrict__ h,
        const float* __restrict__ W1, const float* __restrict__ b1,
        u16* __restrict__ z) {
    __shared__ float sm[4][64];
    int wid = threadIdx.x >> 6, lane = threadIdx.x & 63;
    int node = blockIdx.x * 4 + wid;                 // 25000 blocks x 4 = NN
    int deg = cnt_r[node];
    if (deg > MCAP) deg = MCAP;
    const int* __restrict__ row = bucket + node * MCAP;

    int my = 0; float rq = 0.f;
    if (lane < deg) {
        my = row[lane];                              // batched edge srcs (deg <= 64)
        rq = rnorm_s[my];                            // batched sender norms
    }
    int qtr = lane >> 4, ql = lane & 15;
    float a0 = 0.f, a1 = 0.f, a2 = 0.f, a3 = 0.f;
    for (int j = 0; j < deg; j += 4) {
        int ei = j + qtr;
        int src = __shfl(my, ei, 64);
        float rs = __shfl(rq, ei, 64);
        uint2 w2 = *(const uint2*)(h + (size_t)src * D + ql * 4);  // 4 bf16 feats
        if (ei < deg) {
            a0 = fmaf(rs, bf2f(w2.x & 0xffffu), a0);
            a1 = fmaf(rs, bf2f(w2.x >> 16),     a1);
            a2 = fmaf(rs, bf2f(w2.y & 0xffffu), a2);
            a3 = fmaf(rs, bf2f(w2.y >> 16),     a3);
        }
    }
    a0 += __shfl_xor(a0, 16, 64); a0 += __shfl_xor(a0, 32, 64);
    a1 += __shfl_xor(a1, 16, 64); a1 += __shfl_xor(a1, 32, 64);
    a2 += __shfl_xor(a2, 16, 64); a2 += __shfl_xor(a2, 32, 64);
    a3 += __shfl_xor(a3, 16, 64); a3 += __shfl_xor(a3, 32, 64);
    if (qtr == 0) {
        float rn = rsqrtf((float)(deg > 1 ? deg : 1));
        float v0 = a0 * rn; v0 = (v0 >= 0.f) ? v0 : NEG_SLOPE * v0;
        float v1 = a1 * rn; v1 = (v1 >= 0.f) ? v1 : NEG_SLOPE * v1;
        float v2 = a2 * rn; v2 = (v2 >= 0.f) ? v2 : NEG_SLOPE * v2;
        float v3 = a3 * rn; v3 = (v3 >= 0.f) ? v3 : NEG_SLOPE * v3;
        sm[wid][ql * 4 + 0] = v0;
        sm[wid][ql * 4 + 1] = v1;
        sm[wid][ql * 4 + 2] = v2;
        sm[wid][ql * 4 + 3] = v3;
    }
    __syncthreads();   // all threads reach

    // layer 2 in-wave: class c = lane&15, quarter q covers 16 feats
    int c = lane & 15, q = lane >> 4;
    float p = 0.f;
#pragma unroll
    for (int i = 0; i < 16; ++i)
        p = fmaf(sm[wid][q * 16 + i], W1[(q * 16 + i) * C + c], p);
    p += __shfl_xor(p, 16, 64);
    p += __shfl_xor(p, 32, 64);
    if (lane < 16) {
        float zc = 1.f / (1.f + expf(-(p + b1[c])));
        z[(size_t)node * C + c] = f2bf(zc);
    }
}

// ==== kC: agg2 of bf16 z -> out; 16 edges per wave-step via uint2 ====
__global__ __launch_bounds__(256) void kC(
        const int* __restrict__ cnt_r, const int* __restrict__ bucket,
        const u16* __restrict__ z, float* __restrict__ out) {
    int idx = blockIdx.x * 256 + threadIdx.x;
    int node = idx >> 6;                             // 25000 blocks -> NN nodes
    int lane = threadIdx.x & 63;
    int deg = cnt_r[node];
    if (deg > MCAP) deg = MCAP;
    const int* __restrict__ row = bucket + node * MCAP;

    int my = (lane < deg) ? row[lane] : 0;
    int g = lane >> 2, p = lane & 3;                 // 16 edge-groups x 4 class-quads
    float a0 = 0.f, a1 = 0.f, a2 = 0.f, a3 = 0.f;
    for (int j = 0; j < deg; j += 16) {
        int ei = j + g;
        int src = __shfl(my, ei, 64);
        uint2 w2 = *(const uint2*)(z + (size_t)src * C + p * 4);  // 4 bf16 classes
        if (ei < deg) {
            a0 += bf2f(w2.x & 0xffffu);
            a1 += bf2f(w2.x >> 16);
            a2 += bf2f(w2.y & 0xffffu);
            a3 += bf2f(w2.y >> 16);
        }
    }
    a0 += __shfl_xor(a0, 4, 64); a0 += __shfl_xor(a0, 8, 64);
    a0 += __shfl_xor(a0, 16, 64); a0 += __shfl_xor(a0, 32, 64);
    a1 += __shfl_xor(a1, 4, 64); a1 += __shfl_xor(a1, 8, 64);
    a1 += __shfl_xor(a1, 16, 64); a1 += __shfl_xor(a1, 32, 64);
    a2 += __shfl_xor(a2, 4, 64); a2 += __shfl_xor(a2, 8, 64);
    a2 += __shfl_xor(a2, 16, 64); a2 += __shfl_xor(a2, 32, 64);
    a3 += __shfl_xor(a3, 4, 64); a3 += __shfl_xor(a3, 8, 64);
    a3 += __shfl_xor(a3, 16, 64); a3 += __shfl_xor(a3, 32, 64);
    if (lane < 4) {   // g==0, p=lane: classes [p*4, p*4+4)
        float4 o; o.x = a0; o.y = a1; o.z = a2; o.w = a3;
        *(float4*)(out + (size_t)node * C + p * 4) = o;   // written exactly once
    }
}

extern "C" void kernel_launch(void* const* d_in, const int* in_sizes, int n_in,
                              void* d_out, int out_size, void* d_ws, size_t ws_size,
                              hipStream_t stream) {
    const float* nodes     = (const float*)d_in[0];
    const int*   senders   = (const int*)d_in[1];
    const int*   receivers = (const int*)d_in[2];
    const float* W0        = (const float*)d_in[3];
    const float* b0        = (const float*)d_in[4];
    const float* W1        = (const float*)d_in[5];
    const float* b1        = (const float*)d_in[6];
    float* out = (float*)d_out;

    // workspace layout (~48.8 MB)
    char* wsb = (char*)d_ws;
    int*   cnt_r   = (int*)wsb;                           // 400,000 B
    u32*   part    = (u32*)(wsb + 400000);                // 512*3136*4 = 6,422,528 B
    float* rnorm_s = (float*)(wsb + 6822528);             // 400,000 B
    int*   bucket  = (int*)(wsb + 7222528);               // 25,600,000 B
    u16*   h       = (u16*)(wsb + 32822528);              // 12,800,000 B
    u16*   z       = (u16*)(wsb + 45622528);              // 3,200,000 B

    hipMemsetAsync(cnt_r, 0, NN * sizeof(int), stream);

    // build (even) + gemm (odd) interleaved, hist blocks last
    kA<<<2 * B_BUILD + B_HIST, 256, 0, stream>>>(senders, receivers, nodes, W0, b0,
                                                 cnt_r, bucket, h, part);
    k0b<<<98, 256, 0, stream>>>(part, rnorm_s);
    kB<<<25000, 256, 0, stream>>>(cnt_r, bucket, rnorm_s, h, W1, b1, z);
    kC<<<25000, 256, 0, stream>>>(cnt_r, bucket, z, out);
}